// Round 9
// baseline (336.503 us; speedup 1.0000x reference)
//
#include <hip/hip_runtime.h>
#include <hip/hip_bf16.h>
#include <float.h>
#include <math.h>

// Problem dims (fixed by reference)
constexpr int B  = 4;
constexpr int D  = 512;
constexpr int C  = 2;
constexpr int Dc = 256;     // D / C
constexpr int FT = 256 * 256;   // 65536
constexpr int HW = 14 * 14;     // 196
constexpr int OUTC = 2 * Dc + D;  // 1024 output channels
constexpr float EPSV = 1e-8f;

typedef float f4 __attribute__((ext_vector_type(4)));

// ws layout (floats):
//   xp   @ 0    : 2048   xp[b*D + d]
//   mind @ 2048 : 8 ints

// Kernel A: fused max-reduce over (F,T) + copy x -> out[:, 2*Dc + d].
// Config: NT loads + NT stores (hint matrix explored R2/R5/R8: NT/NT best),
// unroll 16 (R7), 4 partial max accumulators (break serial fmax chain).
__global__ __launch_bounds__(256) void kA_maxcopy(const float* __restrict__ x,
                                                  float* __restrict__ out,
                                                  float* __restrict__ xp) {
    const int slice = blockIdx.x;            // b*D + d
    const int b = slice / D;
    const int d = slice % D;
    const f4* xs = (const f4*)(x + (size_t)slice * FT);
    f4* os = (f4*)(out + ((size_t)(b * OUTC + 2 * Dc + d)) * FT);
    float m0 = -FLT_MAX, m1 = -FLT_MAX, m2 = -FLT_MAX, m3 = -FLT_MAX;
    // FT/4 = 16384 f4 elements; 256 threads x 16-deep unroll x 4 outer iters
    for (int i0 = threadIdx.x; i0 < FT / 4; i0 += 256 * 16) {
        f4 v[16];
        #pragma unroll
        for (int u = 0; u < 16; ++u)
            v[u] = __builtin_nontemporal_load(&xs[i0 + u * 256]);
        #pragma unroll
        for (int u = 0; u < 16; ++u) {
            __builtin_nontemporal_store(v[u], &os[i0 + u * 256]);
            float mv = fmaxf(fmaxf(v[u].x, v[u].y), fmaxf(v[u].z, v[u].w));
            if ((u & 3) == 0)      m0 = fmaxf(m0, mv);
            else if ((u & 3) == 1) m1 = fmaxf(m1, mv);
            else if ((u & 3) == 2) m2 = fmaxf(m2, mv);
            else                   m3 = fmaxf(m3, mv);
        }
    }
    float m = fmaxf(fmaxf(m0, m1), fmaxf(m2, m3));
    // wave (64) reduce then cross-wave via LDS
    for (int off = 32; off; off >>= 1) m = fmaxf(m, __shfl_down(m, off, 64));
    __shared__ float sm[4];
    if ((threadIdx.x & 63) == 0) sm[threadIdx.x >> 6] = m;
    __syncthreads();
    if (threadIdx.x == 0) {
        xp[slice] = fmaxf(fmaxf(sm[0], sm[1]), fmaxf(sm[2], sm[3]));
    }
}

// Kernel BC: single block — norms, dots, maps, argmax, scores, loss,
// att_maps, mind. (Logic field-proven as the R5 fold block.)
__global__ __launch_bounds__(256) void kBC(const float* __restrict__ v0,
                                           const float* __restrict__ v1,
                                           const float* __restrict__ xp,
                                           float* __restrict__ out,
                                           int* __restrict__ mind) {
    const int tid = threadIdx.x;

    __shared__ float sxp[2048];                // all of xp
    __shared__ float smaps[16 * HW];           // maps[b][p][c][hw]
    __shared__ float s_xn[8];
    __shared__ float s_mx[16];
    __shared__ int   s_ai[16];
    __shared__ int   s_pb[B];
    __shared__ float cand_v[256];
    __shared__ int   cand_i[256];

    #pragma unroll
    for (int k = 0; k < 8; ++k) sxp[tid + k * 256] = xp[tid + k * 256];
    __syncthreads();

    // norms of xp[b,c,:] — 8 groups of 32 lanes; group g = b*2+c
    {
        const int g = tid >> 5, l = tid & 31;
        float acc = 0.f;
        for (int dc = l; dc < Dc; dc += 32) {
            float v = sxp[g * Dc + dc];
            acc = fmaf(v, v, acc);
        }
        for (int off = 16; off; off >>= 1) acc += __shfl_down(acc, off, 32);
        if (l == 0) s_xn[g] = sqrtf(acc);
    }
    __syncthreads();

    // dots + maps: group g=(b,c) of 32 lanes; each lane strides hw
    {
        const int g = tid >> 5, l = tid & 31;
        const int bb = g >> 1, c = g & 1;
        const float* vv = (c == 0 ? v0 : v1) + (size_t)bb * Dc * HW;
        const float* xc = sxp + (bb * C + c) * Dc;
        const float* xo = sxp + (bb * C + (1 - c)) * Dc;
        const float xn_c = s_xn[bb * C + c];       // xn[b,0,c]
        const float xn_o = s_xn[bb * C + (1 - c)]; // xn[b,1,c]
        for (int hw = l; hw < HW; hw += 32) {
            float d0 = 0.f, d1 = 0.f, vs = 0.f;
            for (int dc = 0; dc < Dc; ++dc) {
                float v = vv[dc * HW + hw];
                d0 = fmaf(xc[dc], v, d0);
                d1 = fmaf(xo[dc], v, d1);
                vs = fmaf(v, v, vs);
            }
            const float vn = sqrtf(vs);
            smaps[(bb * 4 + 0 * 2 + c) * HW + hw] = d0 / fmaxf(xn_c * vn, EPSV);
            smaps[(bb * 4 + 1 * 2 + c) * HW + hw] = d1 / fmaxf(xn_o * vn, EPSV);
        }
    }
    __syncthreads();

    // max + first-index argmax per row (16 rows x 196), 16 threads/row
    {
        const int row = tid >> 4, sub = tid & 15;
        float bv = -FLT_MAX; int bi = HW;
        for (int hw = sub; hw < HW; hw += 16) {
            float v = smaps[row * HW + hw];
            if (v > bv) { bv = v; bi = hw; }
        }
        cand_v[tid] = bv; cand_i[tid] = bi;
        __syncthreads();
        if (sub == 0) {
            float mv = -FLT_MAX; int mi = 0;
            for (int k = 0; k < 16; ++k) {
                float v = cand_v[row * 16 + k]; int idx = cand_i[row * 16 + k];
                if (v > mv || (v == mv && idx < mi)) { mv = v; mi = idx; }
            }
            s_mx[row] = mv; s_ai[row] = mi;
        }
    }
    __syncthreads();

    if (tid == 0) {
        float L = 0.f;
        for (int bb = 0; bb < B; ++bb) {
            const float s0 = s_mx[bb * 4 + 0] + s_mx[bb * 4 + 1];
            const float s1 = s_mx[bb * 4 + 2] + s_mx[bb * 4 + 3];
            const int p = (s1 > s0) ? 1 : 0;   // stable argsort(-scores): tie -> p=0
            s_pb[bb] = p;
            L += p ? (s0 - s1) : (s1 - s0);
        }
        out[(size_t)B * OUTC * FT] = L / (float)B;   // match_loss
    }
    __syncthreads();

    const size_t att_off = (size_t)B * OUTC * FT + 1;
    for (int i = tid; i < B * C * HW; i += 256) {
        const int bb = i / (C * HW);
        const int r = i % (C * HW);
        const int c = r / HW, hw = r % HW;
        out[att_off + i] = smaps[(bb * 4 + s_pb[bb] * 2 + c) * HW + hw];
    }
    if (tid < B * C) {
        const int bb = tid / C, c = tid % C;
        mind[tid] = s_ai[bb * 4 + s_pb[bb] * 2 + c];
    }
}

// Kernel D: broadcast-fill out[:, 0:2*Dc] with selected v values (NT stores)
__global__ __launch_bounds__(256) void kD_fill(const float* __restrict__ v0,
                                               const float* __restrict__ v1,
                                               const int* __restrict__ mind,
                                               float* __restrict__ out) {
    const int n = blockIdx.x;               // b*(2*Dc) + c*Dc + dc
    const int b = n / (2 * Dc);
    const int r = n % (2 * Dc);
    const int c = r / Dc;
    const int dc = r % Dc;
    const int hw = mind[b * C + c];
    const float* vv = (c == 0 ? v0 : v1);
    const float val = vv[((size_t)(b * Dc + dc)) * HW + hw];
    f4 v4 = {val, val, val, val};
    f4* os = (f4*)(out + ((size_t)(b * OUTC + c * Dc + dc)) * FT);
    for (int i0 = threadIdx.x; i0 < FT / 4; i0 += 256 * 8) {
        #pragma unroll
        for (int u = 0; u < 8; ++u)
            __builtin_nontemporal_store(v4, &os[i0 + u * 256]);
    }
}

extern "C" void kernel_launch(void* const* d_in, const int* in_sizes, int n_in,
                              void* d_out, int out_size, void* d_ws, size_t ws_size,
                              hipStream_t stream) {
    const float* x  = (const float*)d_in[0];
    const float* v0 = (const float*)d_in[1];
    const float* v1 = (const float*)d_in[2];
    float* out = (float*)d_out;
    float* ws = (float*)d_ws;

    float* xp   = ws;                 // 2048 floats
    int*   mind = (int*)(ws + 2048);  // 8 ints

    kA_maxcopy<<<B * D, 256, 0, stream>>>(x, out, xp);
    kBC<<<1, 256, 0, stream>>>(v0, v1, xp, out, mind);
    kD_fill<<<B * 2 * Dc, 256, 0, stream>>>(v0, v1, mind, out);
}

// Round 10
// 297.033 us; speedup vs baseline: 1.1329x; 1.1329x over previous
//
#include <hip/hip_runtime.h>
#include <hip/hip_bf16.h>
#include <float.h>
#include <math.h>

// Problem dims (fixed by reference)
constexpr int B  = 4;
constexpr int D  = 512;
constexpr int C  = 2;
constexpr int Dc = 256;     // D / C
constexpr int FT = 256 * 256;   // 65536
constexpr int HW = 14 * 14;     // 196
constexpr int OUTC = 2 * Dc + D;  // 1024 output channels
constexpr float EPSV = 1e-8f;

typedef float f4 __attribute__((ext_vector_type(4)));

// Workspace layout (floats):
//   xp    @ 0      : B*D   = 2048
//   maps  @ 2048   : B*2*C*HW = 3136
//   mx    @ 5184   : B*2*C = 16
//   amax  @ 5200   : 16 (int)

// Kernel A: fused max-reduce over (F,T) + copy x -> out[:, 2*Dc + d].
// EXACT R7 config (measured 299 µs): NT loads + NT stores, unroll 16,
// single max chain. (R9's 4-acc variant + kBC fold regressed; reverted.)
__global__ __launch_bounds__(256) void kA_maxcopy(const float* __restrict__ x,
                                                  float* __restrict__ out,
                                                  float* __restrict__ xp) {
    const int slice = blockIdx.x;            // b*D + d
    const int b = slice / D;
    const int d = slice % D;
    const f4* xs = (const f4*)(x + (size_t)slice * FT);
    f4* os = (f4*)(out + ((size_t)(b * OUTC + 2 * Dc + d)) * FT);
    float m = -FLT_MAX;
    // FT/4 = 16384 f4 elements; 256 threads x 16-deep unroll x 4 outer iters
    for (int i0 = threadIdx.x; i0 < FT / 4; i0 += 256 * 16) {
        f4 v[16];
        #pragma unroll
        for (int u = 0; u < 16; ++u)
            v[u] = __builtin_nontemporal_load(&xs[i0 + u * 256]);
        #pragma unroll
        for (int u = 0; u < 16; ++u) {
            __builtin_nontemporal_store(v[u], &os[i0 + u * 256]);
            m = fmaxf(m, fmaxf(fmaxf(v[u].x, v[u].y), fmaxf(v[u].z, v[u].w)));
        }
    }
    // wave (64) reduce then cross-wave via LDS
    for (int off = 32; off; off >>= 1) m = fmaxf(m, __shfl_down(m, off, 64));
    __shared__ float sm[4];
    if ((threadIdx.x & 63) == 0) sm[threadIdx.x >> 6] = m;
    __syncthreads();
    if (threadIdx.x == 0) {
        xp[slice] = fmaxf(fmaxf(sm[0], sm[1]), fmaxf(sm[2], sm[3]));
    }
}

// Kernel B: per (b,c) block — dots, norms, maps, per-(b,p,c) max/argmax
// (EXACT R7 code — 8 blocks, proven fast; R9 showed 1-block fold costs ~30 µs)
__global__ __launch_bounds__(256) void kB_maps(const float* __restrict__ v0,
                                               const float* __restrict__ v1,
                                               const float* __restrict__ xp,
                                               float* __restrict__ maps,
                                               float* __restrict__ mx,
                                               int* __restrict__ amax) {
    const int bc = blockIdx.x;
    const int b = bc / C, c = bc % C;
    const int tid = threadIdx.x;          // blockDim.x == 256 == Dc

    __shared__ float sxc[Dc], sxo[Dc];
    sxc[tid] = xp[(b * C + c) * Dc + tid];         // xp[b, c, :]
    sxo[tid] = xp[(b * C + (1 - c)) * Dc + tid];   // xp[b, 1-c, :]
    __syncthreads();

    float ec = sxc[tid] * sxc[tid];
    float eo = sxo[tid] * sxo[tid];
    for (int off = 32; off; off >>= 1) {
        ec += __shfl_down(ec, off, 64);
        eo += __shfl_down(eo, off, 64);
    }
    __shared__ float red[8];
    const int lane = tid & 63, wid = tid >> 6;
    if (lane == 0) { red[wid] = ec; red[4 + wid] = eo; }
    __syncthreads();
    __shared__ float s_xn_c, s_xn_o;
    if (tid == 0) {
        s_xn_c = sqrtf(red[0] + red[1] + red[2] + red[3]);  // xn[b,0,c]
        s_xn_o = sqrtf(red[4] + red[5] + red[6] + red[7]);  // xn[b,1,c]
    }
    __syncthreads();
    const float xn_c = s_xn_c, xn_o = s_xn_o;

    float map0 = -FLT_MAX, map1 = -FLT_MAX;
    if (tid < HW) {
        const float* vv = (c == 0 ? v0 : v1) + (size_t)b * Dc * HW;
        float d0 = 0.f, d1 = 0.f, vs = 0.f;
        for (int dc = 0; dc < Dc; ++dc) {
            float v = vv[dc * HW + tid];
            d0 = fmaf(sxc[dc], v, d0);
            d1 = fmaf(sxo[dc], v, d1);
            vs = fmaf(v, v, vs);
        }
        float vn = sqrtf(vs);
        map0 = d0 / fmaxf(xn_c * vn, EPSV);
        map1 = d1 / fmaxf(xn_o * vn, EPSV);
        maps[((b * 2 + 0) * C + c) * HW + tid] = map0;
        maps[((b * 2 + 1) * C + c) * HW + tid] = map1;
    }

    __shared__ float rv[256];
    __shared__ int ri[256];
    for (int p = 0; p < 2; ++p) {
        __syncthreads();
        rv[tid] = (tid < HW) ? (p == 0 ? map0 : map1) : -FLT_MAX;
        ri[tid] = tid;
        __syncthreads();
        for (int s = 128; s; s >>= 1) {
            if (tid < s) {
                float v2 = rv[tid + s]; int i2 = ri[tid + s];
                if (v2 > rv[tid] || (v2 == rv[tid] && i2 < ri[tid])) {
                    rv[tid] = v2; ri[tid] = i2;
                }
            }
            __syncthreads();
        }
        if (tid == 0) {
            mx[(b * 2 + p) * C + c] = rv[0];
            amax[(b * 2 + p) * C + c] = ri[0];
        }
    }
}

// Kernel D': broadcast-fill out[:, 0:2*Dc]; selection logic derived
// REDUNDANTLY per block from mx/amax (32 L2-cached scalars — free),
// eliminating kC's launch. Block 0 additionally writes loss + att_maps.
__global__ __launch_bounds__(256) void kD_fill_sel(const float* __restrict__ v0,
                                                   const float* __restrict__ v1,
                                                   const float* __restrict__ maps,
                                                   const float* __restrict__ mx,
                                                   const int* __restrict__ amax,
                                                   float* __restrict__ out) {
    const int n = blockIdx.x;               // b*(2*Dc) + c*Dc + dc
    const int b = n / (2 * Dc);
    const int r = n % (2 * Dc);
    const int c = r / Dc;
    const int dc = r % Dc;
    const int tid = threadIdx.x;

    // derive selection for this block's b (uniform across threads)
    const float s0 = mx[(b * 2 + 0) * C + 0] + mx[(b * 2 + 0) * C + 1];
    const float s1 = mx[(b * 2 + 1) * C + 0] + mx[(b * 2 + 1) * C + 1];
    const int p = (s1 > s0) ? 1 : 0;        // stable argsort(-scores): tie -> p=0
    const int hw = amax[(b * 2 + p) * C + c];

    const float* vv = (c == 0 ? v0 : v1);
    const float val = vv[((size_t)(b * Dc + dc)) * HW + hw];
    f4 v4 = {val, val, val, val};
    f4* os = (f4*)(out + ((size_t)(b * OUTC + c * Dc + dc)) * FT);
    for (int i0 = tid; i0 < FT / 4; i0 += 256 * 8) {
        #pragma unroll
        for (int u = 0; u < 8; ++u)
            __builtin_nontemporal_store(v4, &os[i0 + u * 256]);
    }

    // block 0: match_loss + att_maps (former kC epilogue)
    if (n == 0) {
        if (tid == 0) {
            float L = 0.f;
            for (int bb = 0; bb < B; ++bb) {
                const float t0 = mx[(bb * 2 + 0) * C + 0] + mx[(bb * 2 + 0) * C + 1];
                const float t1 = mx[(bb * 2 + 1) * C + 0] + mx[(bb * 2 + 1) * C + 1];
                const int pb = (t1 > t0) ? 1 : 0;
                L += pb ? (t0 - t1) : (t1 - t0);
            }
            out[(size_t)B * OUTC * FT] = L / (float)B;
        }
        const size_t att_off = (size_t)B * OUTC * FT + 1;
        for (int i = tid; i < B * C * HW; i += 256) {
            const int bb = i / (C * HW);
            const int rr = i % (C * HW);
            const int cc = rr / HW, hh = rr % HW;
            const float t0 = mx[(bb * 2 + 0) * C + 0] + mx[(bb * 2 + 0) * C + 1];
            const float t1 = mx[(bb * 2 + 1) * C + 0] + mx[(bb * 2 + 1) * C + 1];
            const int pb = (t1 > t0) ? 1 : 0;
            out[att_off + i] = maps[((bb * 2 + pb) * C + cc) * HW + hh];
        }
    }
}

extern "C" void kernel_launch(void* const* d_in, const int* in_sizes, int n_in,
                              void* d_out, int out_size, void* d_ws, size_t ws_size,
                              hipStream_t stream) {
    const float* x  = (const float*)d_in[0];
    const float* v0 = (const float*)d_in[1];
    const float* v1 = (const float*)d_in[2];
    float* out = (float*)d_out;
    float* ws = (float*)d_ws;

    float* xp   = ws;                 // 2048
    float* maps = ws + 2048;          // 3136
    float* mx   = ws + 5184;          // 16
    int*   amax = (int*)(ws + 5200);  // 16

    kA_maxcopy<<<B * D, 256, 0, stream>>>(x, out, xp);
    kB_maps<<<B * C, 256, 0, stream>>>(v0, v1, xp, maps, mx, amax);
    kD_fill_sel<<<B * 2 * Dc, 256, 0, stream>>>(v0, v1, maps, mx, amax, out);
}

// Round 11
// 293.555 us; speedup vs baseline: 1.1463x; 1.0118x over previous
//
#include <hip/hip_runtime.h>
#include <hip/hip_bf16.h>
#include <float.h>
#include <math.h>

// Problem dims (fixed by reference)
constexpr int B  = 4;
constexpr int D  = 512;
constexpr int C  = 2;
constexpr int Dc = 256;     // D / C
constexpr int FT = 256 * 256;   // 65536
constexpr int HW = 14 * 14;     // 196
constexpr int OUTC = 2 * Dc + D;  // 1024 output channels
constexpr float EPSV = 1e-8f;

typedef float f4 __attribute__((ext_vector_type(4)));

// Workspace layout (floats):
//   xp    @ 0      : B*D   = 2048
//   maps  @ 2048   : B*2*C*HW = 3136
//   mx    @ 5184   : B*2*C = 16
//   amax  @ 5200   : 16 (int)

// Kernel A: fused max-reduce over (F,T) + copy x -> out[:, 2*Dc + d].
// NT loads + NT stores (proven R2/R5/R8). R11 change: SOFTWARE PIPELINE —
// issue batch i+1's 8 loads BEFORE batch i's store burst, so the read
// stream never drains during stores (counted vmcnt instead of full drain).
__global__ __launch_bounds__(256) void kA_maxcopy(const float* __restrict__ x,
                                                  float* __restrict__ out,
                                                  float* __restrict__ xp) {
    const int slice = blockIdx.x;            // b*D + d
    const int b = slice / D;
    const int d = slice % D;
    const f4* xs = (const f4*)(x + (size_t)slice * FT);
    f4* os = (f4*)(out + ((size_t)(b * OUTC + 2 * Dc + d)) * FT);
    const int tid = threadIdx.x;
    float m = -FLT_MAX;

    // 16384 f4 per slice; batch = 256 threads x 8 = 2048 f4; 8 batches.
    f4 cur[8], nxt[8];
    #pragma unroll
    for (int u = 0; u < 8; ++u)
        cur[u] = __builtin_nontemporal_load(&xs[tid + u * 256]);

    #pragma unroll
    for (int it = 0; it < 8; ++it) {
        const int i0 = tid + it * 2048;
        if (it < 7) {
            const int i1 = i0 + 2048;
            #pragma unroll
            for (int u = 0; u < 8; ++u)
                nxt[u] = __builtin_nontemporal_load(&xs[i1 + u * 256]);
        }
        #pragma unroll
        for (int u = 0; u < 8; ++u) {
            __builtin_nontemporal_store(cur[u], &os[i0 + u * 256]);
            m = fmaxf(m, fmaxf(fmaxf(cur[u].x, cur[u].y), fmaxf(cur[u].z, cur[u].w)));
        }
        #pragma unroll
        for (int u = 0; u < 8; ++u) cur[u] = nxt[u];
    }

    // wave (64) reduce then cross-wave via LDS
    for (int off = 32; off; off >>= 1) m = fmaxf(m, __shfl_down(m, off, 64));
    __shared__ float sm[4];
    if ((tid & 63) == 0) sm[tid >> 6] = m;
    __syncthreads();
    if (tid == 0) {
        xp[slice] = fmaxf(fmaxf(sm[0], sm[1]), fmaxf(sm[2], sm[3]));
    }
}

// Kernel B: per (b,c) block — dots, norms, maps, per-(b,p,c) max/argmax
// (EXACT R7/R10 code — 8 blocks, proven)
__global__ __launch_bounds__(256) void kB_maps(const float* __restrict__ v0,
                                               const float* __restrict__ v1,
                                               const float* __restrict__ xp,
                                               float* __restrict__ maps,
                                               float* __restrict__ mx,
                                               int* __restrict__ amax) {
    const int bc = blockIdx.x;
    const int b = bc / C, c = bc % C;
    const int tid = threadIdx.x;          // blockDim.x == 256 == Dc

    __shared__ float sxc[Dc], sxo[Dc];
    sxc[tid] = xp[(b * C + c) * Dc + tid];         // xp[b, c, :]
    sxo[tid] = xp[(b * C + (1 - c)) * Dc + tid];   // xp[b, 1-c, :]
    __syncthreads();

    float ec = sxc[tid] * sxc[tid];
    float eo = sxo[tid] * sxo[tid];
    for (int off = 32; off; off >>= 1) {
        ec += __shfl_down(ec, off, 64);
        eo += __shfl_down(eo, off, 64);
    }
    __shared__ float red[8];
    const int lane = tid & 63, wid = tid >> 6;
    if (lane == 0) { red[wid] = ec; red[4 + wid] = eo; }
    __syncthreads();
    __shared__ float s_xn_c, s_xn_o;
    if (tid == 0) {
        s_xn_c = sqrtf(red[0] + red[1] + red[2] + red[3]);  // xn[b,0,c]
        s_xn_o = sqrtf(red[4] + red[5] + red[6] + red[7]);  // xn[b,1,c]
    }
    __syncthreads();
    const float xn_c = s_xn_c, xn_o = s_xn_o;

    float map0 = -FLT_MAX, map1 = -FLT_MAX;
    if (tid < HW) {
        const float* vv = (c == 0 ? v0 : v1) + (size_t)b * Dc * HW;
        float d0 = 0.f, d1 = 0.f, vs = 0.f;
        for (int dc = 0; dc < Dc; ++dc) {
            float v = vv[dc * HW + tid];
            d0 = fmaf(sxc[dc], v, d0);
            d1 = fmaf(sxo[dc], v, d1);
            vs = fmaf(v, v, vs);
        }
        float vn = sqrtf(vs);
        map0 = d0 / fmaxf(xn_c * vn, EPSV);
        map1 = d1 / fmaxf(xn_o * vn, EPSV);
        maps[((b * 2 + 0) * C + c) * HW + tid] = map0;
        maps[((b * 2 + 1) * C + c) * HW + tid] = map1;
    }

    __shared__ float rv[256];
    __shared__ int ri[256];
    for (int p = 0; p < 2; ++p) {
        __syncthreads();
        rv[tid] = (tid < HW) ? (p == 0 ? map0 : map1) : -FLT_MAX;
        ri[tid] = tid;
        __syncthreads();
        for (int s = 128; s; s >>= 1) {
            if (tid < s) {
                float v2 = rv[tid + s]; int i2 = ri[tid + s];
                if (v2 > rv[tid] || (v2 == rv[tid] && i2 < ri[tid])) {
                    rv[tid] = v2; ri[tid] = i2;
                }
            }
            __syncthreads();
        }
        if (tid == 0) {
            mx[(b * 2 + p) * C + c] = rv[0];
            amax[(b * 2 + p) * C + c] = ri[0];
        }
    }
}

// Kernel D': broadcast-fill out[:, 0:2*Dc]; selection derived redundantly
// per block from mx/amax; block 0 writes loss + att_maps. (EXACT R10 code.)
__global__ __launch_bounds__(256) void kD_fill_sel(const float* __restrict__ v0,
                                                   const float* __restrict__ v1,
                                                   const float* __restrict__ maps,
                                                   const float* __restrict__ mx,
                                                   const int* __restrict__ amax,
                                                   float* __restrict__ out) {
    const int n = blockIdx.x;               // b*(2*Dc) + c*Dc + dc
    const int b = n / (2 * Dc);
    const int r = n % (2 * Dc);
    const int c = r / Dc;
    const int dc = r % Dc;
    const int tid = threadIdx.x;

    const float s0 = mx[(b * 2 + 0) * C + 0] + mx[(b * 2 + 0) * C + 1];
    const float s1 = mx[(b * 2 + 1) * C + 0] + mx[(b * 2 + 1) * C + 1];
    const int p = (s1 > s0) ? 1 : 0;        // stable argsort(-scores): tie -> p=0
    const int hw = amax[(b * 2 + p) * C + c];

    const float* vv = (c == 0 ? v0 : v1);
    const float val = vv[((size_t)(b * Dc + dc)) * HW + hw];
    f4 v4 = {val, val, val, val};
    f4* os = (f4*)(out + ((size_t)(b * OUTC + c * Dc + dc)) * FT);
    for (int i0 = tid; i0 < FT / 4; i0 += 256 * 8) {
        #pragma unroll
        for (int u = 0; u < 8; ++u)
            __builtin_nontemporal_store(v4, &os[i0 + u * 256]);
    }

    if (n == 0) {
        if (tid == 0) {
            float L = 0.f;
            for (int bb = 0; bb < B; ++bb) {
                const float t0 = mx[(bb * 2 + 0) * C + 0] + mx[(bb * 2 + 0) * C + 1];
                const float t1 = mx[(bb * 2 + 1) * C + 0] + mx[(bb * 2 + 1) * C + 1];
                const int pb = (t1 > t0) ? 1 : 0;
                L += pb ? (t0 - t1) : (t1 - t0);
            }
            out[(size_t)B * OUTC * FT] = L / (float)B;
        }
        const size_t att_off = (size_t)B * OUTC * FT + 1;
        for (int i = tid; i < B * C * HW; i += 256) {
            const int bb = i / (C * HW);
            const int rr = i % (C * HW);
            const int cc = rr / HW, hh = rr % HW;
            const float t0 = mx[(bb * 2 + 0) * C + 0] + mx[(bb * 2 + 0) * C + 1];
            const float t1 = mx[(bb * 2 + 1) * C + 0] + mx[(bb * 2 + 1) * C + 1];
            const int pb = (t1 > t0) ? 1 : 0;
            out[att_off + i] = maps[((bb * 2 + pb) * C + cc) * HW + hh];
        }
    }
}

extern "C" void kernel_launch(void* const* d_in, const int* in_sizes, int n_in,
                              void* d_out, int out_size, void* d_ws, size_t ws_size,
                              hipStream_t stream) {
    const float* x  = (const float*)d_in[0];
    const float* v0 = (const float*)d_in[1];
    const float* v1 = (const float*)d_in[2];
    float* out = (float*)d_out;
    float* ws = (float*)d_ws;

    float* xp   = ws;                 // 2048
    float* maps = ws + 2048;          // 3136
    float* mx   = ws + 5184;          // 16
    int*   amax = (int*)(ws + 5200);  // 16

    kA_maxcopy<<<B * D, 256, 0, stream>>>(x, out, xp);
    kB_maps<<<B * C, 256, 0, stream>>>(v0, v1, xp, maps, mx, amax);
    kD_fill_sel<<<B * 2 * Dc, 256, 0, stream>>>(v0, v1, maps, mx, amax, out);
}